// Round 1
// baseline (308.733 us; speedup 1.0000x reference)
//
#include <hip/hip_runtime.h>

// GenerateNodes: out[n,t,o,k] = sum_c mix[n,t,c] * W[k,o,c] + b[k,o]
// mix = concat(x [16384,3200], seeds [16384,15])  -> GEMM M=16384, K=3215, Ncol=60
// Strategy: bf16 MFMA 16x16x32, A direct-from-global (fp32->bf16 in regs),
// B prepacked to fragment order in d_ws by a prep kernel. No LDS, no barriers.

#define NROWS    16384
#define CIN      3200
#define SEED_K   15
#define LIN_IN   3215
#define NCOL     60
#define KB_MAIN  100          // 3200 / 32
#define KB_TOT   101          // + tail block covering the 15 seed channels
#define WB_ELEMS (KB_TOT * 4 * 64 * 8)   // 206848 ushorts = 413696 B in d_ws

typedef __attribute__((ext_vector_type(8))) __bf16 bf16x8;
typedef __attribute__((ext_vector_type(4))) float f32x4;
typedef __attribute__((ext_vector_type(8))) unsigned short ushort8;

__device__ inline unsigned short f2bf_rne(float f) {
    unsigned int u = __builtin_bit_cast(unsigned int, f);
    u += 0x7fffu + ((u >> 16) & 1u);
    return (unsigned short)(u >> 16);
}

__device__ inline bf16x8 to_bf16x8(f32x4 a0, f32x4 a1) {
    ushort8 u;
    u[0] = f2bf_rne(a0[0]); u[1] = f2bf_rne(a0[1]);
    u[2] = f2bf_rne(a0[2]); u[3] = f2bf_rne(a0[3]);
    u[4] = f2bf_rne(a1[0]); u[5] = f2bf_rne(a1[1]);
    u[6] = f2bf_rne(a1[2]); u[7] = f2bf_rne(a1[3]);
    return __builtin_bit_cast(bf16x8, u);
}

// Pack W[20,3,3215] fp32 into bf16 B-fragment order:
// Wb[kb][nt][lane][jj] = B[k = kb*32 + (lane>>4)*8 + jj][n = nt*16 + (lane&15)]
// where B[c][j] = W[j%20][j/20][c]; zero-pad k>=3215 and n>=60.
__global__ void prep_B(const float* __restrict__ W, unsigned short* __restrict__ Wb) {
    int idx = blockIdx.x * blockDim.x + threadIdx.x;
    if (idx >= WB_ELEMS) return;
    int jj   = idx & 7;
    int lane = (idx >> 3) & 63;
    int nt   = (idx >> 9) & 3;
    int kb   = idx >> 11;
    int k = kb * 32 + (lane >> 4) * 8 + jj;
    int n = nt * 16 + (lane & 15);
    float v = 0.0f;
    if (k < LIN_IN && n < NCOL) {
        int o = n / 20, kn = n % 20;
        v = W[(kn * 3 + o) * LIN_IN + k];
    }
    Wb[idx] = f2bf_rne(v);
}

__global__ __launch_bounds__(256) void gen_nodes_gemm(
    const float* __restrict__ x, const float* __restrict__ seeds,
    const float* __restrict__ b, const unsigned short* __restrict__ Wb,
    float* __restrict__ out) {
    const int lane = threadIdx.x & 63;
    const int wave = threadIdx.x >> 6;
    const int quad = lane >> 4;
    const int l15  = lane & 15;
    const int row_base = blockIdx.x * 64 + wave * 16;   // 16 rows per wave
    const int arow = row_base + l15;                    // A-operand row for this lane

    const float* xrow = x + (size_t)arow * CIN + quad * 8;

    f32x4 acc[4];
#pragma unroll
    for (int i = 0; i < 4; ++i) acc[i] = (f32x4){0.f, 0.f, 0.f, 0.f};

#pragma unroll 4
    for (int kb = 0; kb < KB_MAIN; ++kb) {
        const f32x4* ap = (const f32x4*)(xrow + kb * 32);
        f32x4 a0 = ap[0];
        f32x4 a1 = ap[1];
        const unsigned short* bb = Wb + (size_t)kb * 2048 + lane * 8;
        bf16x8 b0 = *(const bf16x8*)(bb);
        bf16x8 b1 = *(const bf16x8*)(bb + 512);
        bf16x8 b2 = *(const bf16x8*)(bb + 1024);
        bf16x8 b3 = *(const bf16x8*)(bb + 1536);
        bf16x8 af = to_bf16x8(a0, a1);
        acc[0] = __builtin_amdgcn_mfma_f32_16x16x32_bf16(af, b0, acc[0], 0, 0, 0);
        acc[1] = __builtin_amdgcn_mfma_f32_16x16x32_bf16(af, b1, acc[1], 0, 0, 0);
        acc[2] = __builtin_amdgcn_mfma_f32_16x16x32_bf16(af, b2, acc[2], 0, 0, 0);
        acc[3] = __builtin_amdgcn_mfma_f32_16x16x32_bf16(af, b3, acc[3], 0, 0, 0);
    }

    // Tail MFMA block: the 15 seed channels (k = 3200..3214), zero-padded to 32.
    {
        const float* srow = seeds + (size_t)arow * SEED_K;
        f32x4 s0 = {0.f, 0.f, 0.f, 0.f}, s1 = {0.f, 0.f, 0.f, 0.f};
#pragma unroll
        for (int j = 0; j < 4; ++j) {
            int c = quad * 8 + j;
            if (c < SEED_K) s0[j] = srow[c];
            if (c + 4 < SEED_K) s1[j] = srow[c + 4];
        }
        bf16x8 af = to_bf16x8(s0, s1);
        const unsigned short* bb = Wb + (size_t)KB_MAIN * 2048 + lane * 8;
        bf16x8 b0 = *(const bf16x8*)(bb);
        bf16x8 b1 = *(const bf16x8*)(bb + 512);
        bf16x8 b2 = *(const bf16x8*)(bb + 1024);
        bf16x8 b3 = *(const bf16x8*)(bb + 1536);
        acc[0] = __builtin_amdgcn_mfma_f32_16x16x32_bf16(af, b0, acc[0], 0, 0, 0);
        acc[1] = __builtin_amdgcn_mfma_f32_16x16x32_bf16(af, b1, acc[1], 0, 0, 0);
        acc[2] = __builtin_amdgcn_mfma_f32_16x16x32_bf16(af, b2, acc[2], 0, 0, 0);
        acc[3] = __builtin_amdgcn_mfma_f32_16x16x32_bf16(af, b3, acc[3], 0, 0, 0);
    }

    // Epilogue: C/D layout col = lane&15, row = quad*4 + reg.  j = nt*16 + col.
#pragma unroll
    for (int nt = 0; nt < 4; ++nt) {
        int j = nt * 16 + l15;
        if (j < NCOL) {
            float bias = b[(j % 20) * 3 + (j / 20)];
#pragma unroll
            for (int r = 0; r < 4; ++r) {
                int m = quad * 4 + r;
                out[(size_t)(row_base + m) * NCOL + j] = acc[nt][r] + bias;
            }
        }
    }
}

extern "C" void kernel_launch(void* const* d_in, const int* in_sizes, int n_in,
                              void* d_out, int out_size, void* d_ws, size_t ws_size,
                              hipStream_t stream) {
    const float* x     = (const float*)d_in[0];
    const float* seeds = (const float*)d_in[1];
    const float* W     = (const float*)d_in[2];
    const float* b     = (const float*)d_in[3];
    float* out = (float*)d_out;
    unsigned short* Wb = (unsigned short*)d_ws;

    prep_B<<<(WB_ELEMS + 255) / 256, 256, 0, stream>>>(W, Wb);
    gen_nodes_gemm<<<NROWS / 64, 256, 0, stream>>>(x, seeds, b, Wb, out);
}